// Round 6
// baseline (211.990 us; speedup 1.0000x reference)
//
#include <hip/hip_runtime.h>

// Segment-mean pool: x [N][128] f32, batch [N] int32 (sorted, 0..15),
// out [16][128] f32 = segment_sum(x)/max(count,1).
//
// 3-dispatch pipeline:
//   k1 boundary_kernel: int4 scan of sorted batch -> 17 boundary offsets;
//      block 0 also zeroes sums + done counter (replaces memset launch).
//   k2 pool_main: per segment, all 524288 threads (full occupancy) grid-stride
//      linearly over its contiguous float4 range, unroll-2 (2 loads in
//      flight/thread) -> block partials, no global atomics.
//   k3 stage2_div: reduce partials into sums (atomics), last block divides
//      by counts (boundary diffs) and writes out.

#define D       128
#define D4      32
#define BSEG    16
#define BD      (BSEG * D)          // 2048

#define MB_BLOCKS   512
#define MB_THREADS  1024
#define GSTRIDE     (MB_BLOCKS * MB_THREADS)   // 524288 float4s, ≡0 mod 32

// ---- k1: boundaries + zero-init. start[s] = first row of segment s; start[16] = N.
__global__ __launch_bounds__(256)
void boundary_kernel(const int* __restrict__ batch, int N,
                     int* __restrict__ start, float* __restrict__ sums,
                     int* __restrict__ done)
{
    if (blockIdx.x == 0) {
        for (int i = threadIdx.x; i < BD; i += 256) sums[i] = 0.0f;
        if (threadIdx.x == 0) *done = 0;
    }

    int t  = blockIdx.x * 256 + threadIdx.x;
    int i0 = t * 4;
    if (i0 >= N) return;

    int e[5];
    if (i0 + 4 <= N) {
        int4 b = *(const int4*)(batch + i0);
        e[0] = b.x; e[1] = b.y; e[2] = b.z; e[3] = b.w;
    } else {
        for (int k = 0; k < 4; ++k) e[k] = (i0 + k < N) ? batch[i0 + k] : batch[N - 1];
    }
    bool last = (i0 + 4 >= N);
    e[4] = last ? BSEG : batch[i0 + 4];

    if (i0 == 0) {
        int b0 = min(max(e[0], 0), BSEG - 1);
        for (int s = 0; s <= b0; ++s) start[s] = 0;
    }
    for (int k = 0; k < 4; ++k) {
        int a = min(max(e[k], 0), BSEG - 1);
        int b = (k == 3) ? (last ? BSEG : min(max(e[4], 0), BSEG - 1))
                         : min(max(e[k + 1], 0), BSEG - 1);
        int pos = i0 + k + 1; if (pos > N) pos = N;
        for (int s = a + 1; s <= b; ++s) start[s] = pos;
    }
}

// ---- k2: main streaming sum (full occupancy, unroll-2).
__global__ __launch_bounds__(MB_THREADS, 8)
void pool_main(const float4* __restrict__ x4, const int* __restrict__ start,
               float* __restrict__ partial /* [MB_BLOCKS][BD] */)
{
    __shared__ float lds_sum[BSEG][D];
    __shared__ int   lds_st[BSEG + 1];

    const int tid = threadIdx.x;
    for (int i = tid; i < BD; i += MB_THREADS) ((float*)lds_sum)[i] = 0.0f;
    if (tid <= BSEG) lds_st[tid] = start[tid];
    __syncthreads();

    const int gtid = blockIdx.x * MB_THREADS + tid;
    const int col4 = tid & (D4 - 1);      // constant column (GSTRIDE ≡ 0 mod 32)
    const int lane = tid & 63;

    #pragma unroll 1
    for (int s = 0; s < BSEG; ++s) {
        int i = lds_st[s] * D4 + gtid;
        const int e1 = lds_st[s + 1] * D4;          // max 64M, fits int
        float4 a0 = make_float4(0.f, 0.f, 0.f, 0.f);
        float4 a1 = a0;
        for (; i + GSTRIDE < e1; i += 2 * GSTRIDE) {
            float4 v0 = x4[i];
            float4 v1 = x4[i + GSTRIDE];
            a0.x += v0.x; a0.y += v0.y; a0.z += v0.z; a0.w += v0.w;
            a1.x += v1.x; a1.y += v1.y; a1.z += v1.z; a1.w += v1.w;
        }
        if (i < e1) {
            float4 v = x4[i];
            a0.x += v.x; a0.y += v.y; a0.z += v.z; a0.w += v.w;
        }
        a0.x += a1.x; a0.y += a1.y; a0.z += a1.z; a0.w += a1.w;

        // lanes l and l+32 hold the same column: fold within wave
        a0.x += __shfl_down(a0.x, 32);
        a0.y += __shfl_down(a0.y, 32);
        a0.z += __shfl_down(a0.z, 32);
        a0.w += __shfl_down(a0.w, 32);
        if (lane < 32) {
            atomicAdd(&lds_sum[s][col4 * 4 + 0], a0.x);
            atomicAdd(&lds_sum[s][col4 * 4 + 1], a0.y);
            atomicAdd(&lds_sum[s][col4 * 4 + 2], a0.z);
            atomicAdd(&lds_sum[s][col4 * 4 + 3], a0.w);
        }
    }
    __syncthreads();

    // BD floats = 512 float4s: first 512 threads store one float4 each
    if (tid < BD / 4) {
        float4* pp = (float4*)(partial + (long)blockIdx.x * BD);
        pp[tid] = ((const float4*)lds_sum)[tid];
    }
}

// ---- k3: reduce partials, last block divides and writes out.
__global__ __launch_bounds__(256)
void stage2_div(const float* __restrict__ partial, const int* __restrict__ start,
                float* __restrict__ sums, int* __restrict__ done,
                float* __restrict__ out)
{
    __shared__ bool is_last;
    int g   = blockIdx.x * 256 + threadIdx.x;   // 0..32767
    int col = g & (BD - 1);
    int grp = g >> 11;                          // 0..15
    const int rows = MB_BLOCKS / 16;            // 32
    int r0 = grp * rows;
    float s = 0.f;
    for (int k = 0; k < rows; ++k)
        s += partial[(r0 + k) * BD + col];
    atomicAdd(&sums[col], s);

    __threadfence();
    __syncthreads();
    if (threadIdx.x == 0) {
        int t = atomicAdd(done, 1);
        is_last = (t == gridDim.x - 1);
    }
    __syncthreads();
    if (is_last) {
        __threadfence();
        for (int i = threadIdx.x; i < BD; i += 256) {
            float v = __hip_atomic_load(&sums[i], __ATOMIC_ACQUIRE,
                                        __HIP_MEMORY_SCOPE_AGENT);
            int seg = i >> 7;
            float c = (float)(start[seg + 1] - start[seg]);
            out[i] = v / fmaxf(c, 1.0f);
        }
    }
}

// ---------------- fallback (round-1 kernel) if ws is too small --------------
__global__ __launch_bounds__(256)
void pool_sum_fb(const float* __restrict__ x, const int* __restrict__ batch,
                 float* __restrict__ sums, float* __restrict__ counts,
                 int N, int nblocks)
{
    __shared__ float lds_sum[BSEG][D];
    __shared__ float lds_cnt[BSEG];
    const int tid = threadIdx.x;
    for (int i = tid; i < BD; i += 256) ((float*)lds_sum)[i] = 0.0f;
    if (tid < BSEG) lds_cnt[tid] = 0.0f;
    __syncthreads();

    const int chunk = (N + nblocks - 1) / nblocks;
    const int r0 = blockIdx.x * chunk;
    int r1 = r0 + chunk; if (r1 > N) r1 = N;
    const int col4 = tid & (D4 - 1);
    const int rlane = tid >> 5;
    const float4* x4 = (const float4*)x;

    float4 acc = make_float4(0.f, 0.f, 0.f, 0.f);
    int cnt = 0, cur = -1;
    for (int r = r0 + rlane; r < r1; r += 8) {
        int seg = batch[r];
        if (seg != cur) {
            if (cur >= 0) {
                atomicAdd(&lds_sum[cur][col4 * 4 + 0], acc.x);
                atomicAdd(&lds_sum[cur][col4 * 4 + 1], acc.y);
                atomicAdd(&lds_sum[cur][col4 * 4 + 2], acc.z);
                atomicAdd(&lds_sum[cur][col4 * 4 + 3], acc.w);
                if (col4 == 0) atomicAdd(&lds_cnt[cur], (float)cnt);
            }
            acc = make_float4(0.f, 0.f, 0.f, 0.f); cnt = 0;
            cur = (seg >= 0 && seg < BSEG) ? seg : -1;
        }
        if (cur >= 0) {
            float4 v = x4[(long)r * D4 + col4];
            acc.x += v.x; acc.y += v.y; acc.z += v.z; acc.w += v.w; cnt++;
        }
    }
    if (cur >= 0) {
        atomicAdd(&lds_sum[cur][col4 * 4 + 0], acc.x);
        atomicAdd(&lds_sum[cur][col4 * 4 + 1], acc.y);
        atomicAdd(&lds_sum[cur][col4 * 4 + 2], acc.z);
        atomicAdd(&lds_sum[cur][col4 * 4 + 3], acc.w);
        if (col4 == 0) atomicAdd(&lds_cnt[cur], (float)cnt);
    }
    __syncthreads();
    for (int i = tid; i < BD; i += 256) {
        float v = ((float*)lds_sum)[i];
        if (v != 0.0f) atomicAdd(&sums[i], v);
    }
    if (tid < BSEG) {
        float c = lds_cnt[tid];
        if (c != 0.0f) atomicAdd(&counts[tid], c);
    }
}

__global__ __launch_bounds__(256)
void div_fb(const float* __restrict__ sums, const float* __restrict__ counts,
            float* __restrict__ out)
{
    int i = blockIdx.x * 256 + threadIdx.x;
    if (i < BD) out[i] = sums[i] / fmaxf(counts[i >> 7], 1.0f);
}

// ---------------------------------------------------------------------------
extern "C" void kernel_launch(void* const* d_in, const int* in_sizes, int n_in,
                              void* d_out, int out_size, void* d_ws, size_t ws_size,
                              hipStream_t stream)
{
    const float* x     = (const float*)d_in[0];
    const int*   batch = (const int*)d_in[1];
    const int    N     = in_sizes[1];

    // ws layout: [start: 17 ints + done @24][sums: BD floats][partial: MB_BLOCKS*BD]
    int*   start   = (int*)d_ws;
    int*   done    = (int*)d_ws + 24;
    float* sums    = (float*)d_ws + 32;
    float* partial = (float*)d_ws + 32 + BD;
    const size_t need = (size_t)(32 + BD + (size_t)MB_BLOCKS * BD) * sizeof(float);

    if (ws_size >= need) {
        boundary_kernel<<<(N / 4 + 255) / 256, 256, 0, stream>>>(batch, N, start, sums, done);
        pool_main<<<MB_BLOCKS, MB_THREADS, 0, stream>>>((const float4*)x, start, partial);
        stage2_div<<<128, 256, 0, stream>>>(partial, start, sums, done, (float*)d_out);
    } else {
        float* fsums   = (float*)d_ws;
        float* fcounts = fsums + BD;
        hipMemsetAsync(d_ws, 0, (BD + BSEG) * sizeof(float), stream);
        pool_sum_fb<<<2048, 256, 0, stream>>>(x, batch, fsums, fcounts, N, 2048);
        div_fb<<<8, 256, 0, stream>>>(fsums, fcounts, (float*)d_out);
    }
}

// Round 7
// 199.936 us; speedup vs baseline: 1.0603x; 1.0603x over previous
//
#include <hip/hip_runtime.h>

// Segment-mean pool: x [N][128] f32, batch [N] int32 (sorted, 0..15),
// out [16][128] f32 = segment_sum(x)/max(count,1).
//
// 3-dispatch pipeline:
//   k1 boundary_kernel: int4 scan of sorted batch -> 17 boundary offsets;
//      block 0 also zeroes sums + done counter (replaces memset launch).
//   k2 pool_main: per segment, all 524288 threads (full occupancy) grid-stride
//      linearly over its contiguous float4 range (single compact load stream,
//      proven 5.75 TB/s in R5) -> block partials, no global atomics.
//   k3 stage2_div: reduce partials into sums (atomics), last block divides
//      by counts (boundary diffs) and writes out.

#define D       128
#define D4      32
#define BSEG    16
#define BD      (BSEG * D)          // 2048

#define MB_BLOCKS   512
#define MB_THREADS  1024
#define GSTRIDE     (MB_BLOCKS * MB_THREADS)   // 524288 float4s, ≡0 mod 32

// ---- k1: boundaries + zero-init. start[s] = first row of segment s; start[16] = N.
__global__ __launch_bounds__(256)
void boundary_kernel(const int* __restrict__ batch, int N,
                     int* __restrict__ start, float* __restrict__ sums,
                     int* __restrict__ done)
{
    if (blockIdx.x == 0) {
        for (int i = threadIdx.x; i < BD; i += 256) sums[i] = 0.0f;
        if (threadIdx.x == 0) *done = 0;
    }

    int t  = blockIdx.x * 256 + threadIdx.x;
    int i0 = t * 4;
    if (i0 >= N) return;

    int e[5];
    if (i0 + 4 <= N) {
        int4 b = *(const int4*)(batch + i0);
        e[0] = b.x; e[1] = b.y; e[2] = b.z; e[3] = b.w;
    } else {
        for (int k = 0; k < 4; ++k) e[k] = (i0 + k < N) ? batch[i0 + k] : batch[N - 1];
    }
    bool last = (i0 + 4 >= N);
    e[4] = last ? BSEG : batch[i0 + 4];

    if (i0 == 0) {
        int b0 = min(max(e[0], 0), BSEG - 1);
        for (int s = 0; s <= b0; ++s) start[s] = 0;
    }
    for (int k = 0; k < 4; ++k) {
        int a = min(max(e[k], 0), BSEG - 1);
        int b = (k == 3) ? (last ? BSEG : min(max(e[4], 0), BSEG - 1))
                         : min(max(e[k + 1], 0), BSEG - 1);
        int pos = i0 + k + 1; if (pos > N) pos = N;
        for (int s = a + 1; s <= b; ++s) start[s] = pos;
    }
}

// ---- k2: main streaming sum (full occupancy, R5-proven inner loop).
__global__ __launch_bounds__(MB_THREADS, 8)
void pool_main(const float4* __restrict__ x4, const int* __restrict__ start,
               float* __restrict__ partial /* [MB_BLOCKS][BD] */)
{
    __shared__ float lds_sum[BSEG][D];
    __shared__ int   lds_st[BSEG + 1];

    const int tid = threadIdx.x;
    for (int i = tid; i < BD; i += MB_THREADS) ((float*)lds_sum)[i] = 0.0f;
    if (tid <= BSEG) lds_st[tid] = start[tid];
    __syncthreads();

    const int gtid = blockIdx.x * MB_THREADS + tid;
    const int col4 = tid & (D4 - 1);      // constant column (GSTRIDE ≡ 0 mod 32)
    const int lane = tid & 63;

    #pragma unroll 1
    for (int s = 0; s < BSEG; ++s) {
        const int i0 = lds_st[s] * D4 + gtid;
        const int e1 = lds_st[s + 1] * D4;          // max 64M, fits int
        float4 a = make_float4(0.f, 0.f, 0.f, 0.f);
        for (int i = i0; i < e1; i += GSTRIDE) {
            float4 v = x4[i];
            a.x += v.x; a.y += v.y; a.z += v.z; a.w += v.w;
        }
        // lanes l and l+32 hold the same column: fold within wave
        a.x += __shfl_down(a.x, 32);
        a.y += __shfl_down(a.y, 32);
        a.z += __shfl_down(a.z, 32);
        a.w += __shfl_down(a.w, 32);
        if (lane < 32) {
            atomicAdd(&lds_sum[s][col4 * 4 + 0], a.x);
            atomicAdd(&lds_sum[s][col4 * 4 + 1], a.y);
            atomicAdd(&lds_sum[s][col4 * 4 + 2], a.z);
            atomicAdd(&lds_sum[s][col4 * 4 + 3], a.w);
        }
    }
    __syncthreads();

    // BD floats = 512 float4s: first 512 threads store one float4 each
    if (tid < BD / 4) {
        float4* pp = (float4*)(partial + (long)blockIdx.x * BD);
        pp[tid] = ((const float4*)lds_sum)[tid];
    }
}

// ---- k3: reduce partials, last block divides and writes out.
__global__ __launch_bounds__(256)
void stage2_div(const float* __restrict__ partial, const int* __restrict__ start,
                float* __restrict__ sums, int* __restrict__ done,
                float* __restrict__ out)
{
    __shared__ bool is_last;
    int g   = blockIdx.x * 256 + threadIdx.x;   // 0..32767
    int col = g & (BD - 1);
    int grp = g >> 11;                          // 0..15
    const int rows = MB_BLOCKS / 16;            // 32
    int r0 = grp * rows;
    float s = 0.f;
    for (int k = 0; k < rows; ++k)
        s += partial[(r0 + k) * BD + col];
    atomicAdd(&sums[col], s);

    __threadfence();
    __syncthreads();
    if (threadIdx.x == 0) {
        int t = atomicAdd(done, 1);
        is_last = (t == gridDim.x - 1);
    }
    __syncthreads();
    if (is_last) {
        __threadfence();
        for (int i = threadIdx.x; i < BD; i += 256) {
            float v = __hip_atomic_load(&sums[i], __ATOMIC_ACQUIRE,
                                        __HIP_MEMORY_SCOPE_AGENT);
            int seg = i >> 7;
            float c = (float)(start[seg + 1] - start[seg]);
            out[i] = v / fmaxf(c, 1.0f);
        }
    }
}

// ---------------- fallback (round-1 kernel) if ws is too small --------------
__global__ __launch_bounds__(256)
void pool_sum_fb(const float* __restrict__ x, const int* __restrict__ batch,
                 float* __restrict__ sums, float* __restrict__ counts,
                 int N, int nblocks)
{
    __shared__ float lds_sum[BSEG][D];
    __shared__ float lds_cnt[BSEG];
    const int tid = threadIdx.x;
    for (int i = tid; i < BD; i += 256) ((float*)lds_sum)[i] = 0.0f;
    if (tid < BSEG) lds_cnt[tid] = 0.0f;
    __syncthreads();

    const int chunk = (N + nblocks - 1) / nblocks;
    const int r0 = blockIdx.x * chunk;
    int r1 = r0 + chunk; if (r1 > N) r1 = N;
    const int col4 = tid & (D4 - 1);
    const int rlane = tid >> 5;
    const float4* x4 = (const float4*)x;

    float4 acc = make_float4(0.f, 0.f, 0.f, 0.f);
    int cnt = 0, cur = -1;
    for (int r = r0 + rlane; r < r1; r += 8) {
        int seg = batch[r];
        if (seg != cur) {
            if (cur >= 0) {
                atomicAdd(&lds_sum[cur][col4 * 4 + 0], acc.x);
                atomicAdd(&lds_sum[cur][col4 * 4 + 1], acc.y);
                atomicAdd(&lds_sum[cur][col4 * 4 + 2], acc.z);
                atomicAdd(&lds_sum[cur][col4 * 4 + 3], acc.w);
                if (col4 == 0) atomicAdd(&lds_cnt[cur], (float)cnt);
            }
            acc = make_float4(0.f, 0.f, 0.f, 0.f); cnt = 0;
            cur = (seg >= 0 && seg < BSEG) ? seg : -1;
        }
        if (cur >= 0) {
            float4 v = x4[(long)r * D4 + col4];
            acc.x += v.x; acc.y += v.y; acc.z += v.z; acc.w += v.w; cnt++;
        }
    }
    if (cur >= 0) {
        atomicAdd(&lds_sum[cur][col4 * 4 + 0], acc.x);
        atomicAdd(&lds_sum[cur][col4 * 4 + 1], acc.y);
        atomicAdd(&lds_sum[cur][col4 * 4 + 2], acc.z);
        atomicAdd(&lds_sum[cur][col4 * 4 + 3], acc.w);
        if (col4 == 0) atomicAdd(&lds_cnt[cur], (float)cnt);
    }
    __syncthreads();
    for (int i = tid; i < BD; i += 256) {
        float v = ((float*)lds_sum)[i];
        if (v != 0.0f) atomicAdd(&sums[i], v);
    }
    if (tid < BSEG) {
        float c = lds_cnt[tid];
        if (c != 0.0f) atomicAdd(&counts[tid], c);
    }
}

__global__ __launch_bounds__(256)
void div_fb(const float* __restrict__ sums, const float* __restrict__ counts,
            float* __restrict__ out)
{
    int i = blockIdx.x * 256 + threadIdx.x;
    if (i < BD) out[i] = sums[i] / fmaxf(counts[i >> 7], 1.0f);
}

// ---------------------------------------------------------------------------
extern "C" void kernel_launch(void* const* d_in, const int* in_sizes, int n_in,
                              void* d_out, int out_size, void* d_ws, size_t ws_size,
                              hipStream_t stream)
{
    const float* x     = (const float*)d_in[0];
    const int*   batch = (const int*)d_in[1];
    const int    N     = in_sizes[1];

    // ws layout: [start: 17 ints + done @24][sums: BD floats][partial: MB_BLOCKS*BD]
    int*   start   = (int*)d_ws;
    int*   done    = (int*)d_ws + 24;
    float* sums    = (float*)d_ws + 32;
    float* partial = (float*)d_ws + 32 + BD;
    const size_t need = (size_t)(32 + BD + (size_t)MB_BLOCKS * BD) * sizeof(float);

    if (ws_size >= need) {
        boundary_kernel<<<(N / 4 + 255) / 256, 256, 0, stream>>>(batch, N, start, sums, done);
        pool_main<<<MB_BLOCKS, MB_THREADS, 0, stream>>>((const float4*)x, start, partial);
        stage2_div<<<128, 256, 0, stream>>>(partial, start, sums, done, (float*)d_out);
    } else {
        float* fsums   = (float*)d_ws;
        float* fcounts = fsums + BD;
        hipMemsetAsync(d_ws, 0, (BD + BSEG) * sizeof(float), stream);
        pool_sum_fb<<<2048, 256, 0, stream>>>(x, batch, fsums, fcounts, N, 2048);
        div_fb<<<8, 256, 0, stream>>>(fsums, fcounts, (float*)d_out);
    }
}

// Round 8
// 170.992 us; speedup vs baseline: 1.2398x; 1.1693x over previous
//
#include <hip/hip_runtime.h>

// Segment-mean pool: x [N][128] f32, batch [N] int32 (sorted, 0..15),
// out [16][128] f32 = segment_sum(x)/max(count,1).
//
// 4-dispatch pipeline (R5 structure, minus the memset launch):
//   k1 boundary_kernel: int4 scan of sorted batch -> 17 boundary offsets;
//      block 0 also zeroes the sums accumulator (replaces memset launch).
//   k2 pool_main: per segment, all 524288 threads (full occupancy) grid-stride
//      linearly over its contiguous float4 range with NON-TEMPORAL loads
//      (read-once stream; don't churn L2/L3) -> block partials, no atomics.
//   k3 stage2: reduce block partials into sums (global atomics).
//   k4 div: divide by counts (boundary diffs), write out.

#define D       128
#define D4      32
#define BSEG    16
#define BD      (BSEG * D)          // 2048

#define MB_BLOCKS   512
#define MB_THREADS  1024
#define GSTRIDE     (MB_BLOCKS * MB_THREADS)   // 524288 float4s, ≡0 mod 32

typedef float v4f __attribute__((ext_vector_type(4)));

// ---- k1: boundaries + sums zero-init.
__global__ __launch_bounds__(256)
void boundary_kernel(const int* __restrict__ batch, int N,
                     int* __restrict__ start, float* __restrict__ sums)
{
    if (blockIdx.x == 0) {
        for (int i = threadIdx.x; i < BD; i += 256) sums[i] = 0.0f;
    }

    int t  = blockIdx.x * 256 + threadIdx.x;
    int i0 = t * 4;
    if (i0 >= N) return;

    int e[5];
    if (i0 + 4 <= N) {
        int4 b = *(const int4*)(batch + i0);
        e[0] = b.x; e[1] = b.y; e[2] = b.z; e[3] = b.w;
    } else {
        for (int k = 0; k < 4; ++k) e[k] = (i0 + k < N) ? batch[i0 + k] : batch[N - 1];
    }
    bool last = (i0 + 4 >= N);
    e[4] = last ? BSEG : batch[i0 + 4];

    if (i0 == 0) {
        int b0 = min(max(e[0], 0), BSEG - 1);
        for (int s = 0; s <= b0; ++s) start[s] = 0;
    }
    for (int k = 0; k < 4; ++k) {
        int a = min(max(e[k], 0), BSEG - 1);
        int b = (k == 3) ? (last ? BSEG : min(max(e[4], 0), BSEG - 1))
                         : min(max(e[k + 1], 0), BSEG - 1);
        int pos = i0 + k + 1; if (pos > N) pos = N;
        for (int s = a + 1; s <= b; ++s) start[s] = pos;
    }
}

// ---- k2: main streaming sum (full occupancy, nontemporal read-once stream).
__global__ __launch_bounds__(MB_THREADS, 8)
void pool_main(const float* __restrict__ x, const int* __restrict__ start,
               float* __restrict__ partial /* [MB_BLOCKS][BD] */)
{
    __shared__ float lds_sum[BSEG][D];
    __shared__ int   lds_st[BSEG + 1];

    const int tid = threadIdx.x;
    for (int i = tid; i < BD; i += MB_THREADS) ((float*)lds_sum)[i] = 0.0f;
    if (tid <= BSEG) lds_st[tid] = start[tid];
    __syncthreads();

    const int gtid = blockIdx.x * MB_THREADS + tid;
    const int col4 = tid & (D4 - 1);      // constant column (GSTRIDE ≡ 0 mod 32)
    const int lane = tid & 63;

    const v4f* __restrict__ x4 = (const v4f*)x;

    #pragma unroll 1
    for (int s = 0; s < BSEG; ++s) {
        const int i0 = lds_st[s] * D4 + gtid;
        const int e1 = lds_st[s + 1] * D4;          // max 64M, fits int
        v4f a = (v4f)0.0f;
        for (int i = i0; i < e1; i += GSTRIDE) {
            v4f v = __builtin_nontemporal_load(x4 + i);
            a += v;
        }
        // lanes l and l+32 hold the same column: fold within wave
        a.x += __shfl_down(a.x, 32);
        a.y += __shfl_down(a.y, 32);
        a.z += __shfl_down(a.z, 32);
        a.w += __shfl_down(a.w, 32);
        if (lane < 32) {
            atomicAdd(&lds_sum[s][col4 * 4 + 0], a.x);
            atomicAdd(&lds_sum[s][col4 * 4 + 1], a.y);
            atomicAdd(&lds_sum[s][col4 * 4 + 2], a.z);
            atomicAdd(&lds_sum[s][col4 * 4 + 3], a.w);
        }
    }
    __syncthreads();

    // BD floats = 512 float4s: first 512 threads store one float4 each
    if (tid < BD / 4) {
        float4* pp = (float4*)(partial + (long)blockIdx.x * BD);
        pp[tid] = ((const float4*)lds_sum)[tid];
    }
}

// ---- k3: reduce partials.  32768 threads = 2048 cols x 16 row-groups.
__global__ __launch_bounds__(256)
void stage2_kernel(const float* __restrict__ partial, float* __restrict__ sums)
{
    int g   = blockIdx.x * 256 + threadIdx.x;   // 0..32767
    int col = g & (BD - 1);
    int grp = g >> 11;                          // 0..15
    const int rows = MB_BLOCKS / 16;            // 32
    int r0 = grp * rows;
    float s = 0.f;
    for (int k = 0; k < rows; ++k)
        s += partial[(r0 + k) * BD + col];
    atomicAdd(&sums[col], s);
}

// ---- k4: divide by counts derived from boundaries.
__global__ __launch_bounds__(256)
void div_kernel(const float* __restrict__ sums, const int* __restrict__ start,
                float* __restrict__ out)
{
    int i = blockIdx.x * 256 + threadIdx.x;
    if (i < BD) {
        int s = i >> 7;
        float c = (float)(start[s + 1] - start[s]);
        out[i] = sums[i] / fmaxf(c, 1.0f);
    }
}

// ---------------- fallback (round-1 kernel) if ws is too small --------------
__global__ __launch_bounds__(256)
void pool_sum_fb(const float* __restrict__ x, const int* __restrict__ batch,
                 float* __restrict__ sums, float* __restrict__ counts,
                 int N, int nblocks)
{
    __shared__ float lds_sum[BSEG][D];
    __shared__ float lds_cnt[BSEG];
    const int tid = threadIdx.x;
    for (int i = tid; i < BD; i += 256) ((float*)lds_sum)[i] = 0.0f;
    if (tid < BSEG) lds_cnt[tid] = 0.0f;
    __syncthreads();

    const int chunk = (N + nblocks - 1) / nblocks;
    const int r0 = blockIdx.x * chunk;
    int r1 = r0 + chunk; if (r1 > N) r1 = N;
    const int col4 = tid & (D4 - 1);
    const int rlane = tid >> 5;
    const float4* x4 = (const float4*)x;

    float4 acc = make_float4(0.f, 0.f, 0.f, 0.f);
    int cnt = 0, cur = -1;
    for (int r = r0 + rlane; r < r1; r += 8) {
        int seg = batch[r];
        if (seg != cur) {
            if (cur >= 0) {
                atomicAdd(&lds_sum[cur][col4 * 4 + 0], acc.x);
                atomicAdd(&lds_sum[cur][col4 * 4 + 1], acc.y);
                atomicAdd(&lds_sum[cur][col4 * 4 + 2], acc.z);
                atomicAdd(&lds_sum[cur][col4 * 4 + 3], acc.w);
                if (col4 == 0) atomicAdd(&lds_cnt[cur], (float)cnt);
            }
            acc = make_float4(0.f, 0.f, 0.f, 0.f); cnt = 0;
            cur = (seg >= 0 && seg < BSEG) ? seg : -1;
        }
        if (cur >= 0) {
            float4 v = x4[(long)r * D4 + col4];
            acc.x += v.x; acc.y += v.y; acc.z += v.z; acc.w += v.w; cnt++;
        }
    }
    if (cur >= 0) {
        atomicAdd(&lds_sum[cur][col4 * 4 + 0], acc.x);
        atomicAdd(&lds_sum[cur][col4 * 4 + 1], acc.y);
        atomicAdd(&lds_sum[cur][col4 * 4 + 2], acc.z);
        atomicAdd(&lds_sum[cur][col4 * 4 + 3], acc.w);
        if (col4 == 0) atomicAdd(&lds_cnt[cur], (float)cnt);
    }
    __syncthreads();
    for (int i = tid; i < BD; i += 256) {
        float v = ((float*)lds_sum)[i];
        if (v != 0.0f) atomicAdd(&sums[i], v);
    }
    if (tid < BSEG) {
        float c = lds_cnt[tid];
        if (c != 0.0f) atomicAdd(&counts[tid], c);
    }
}

__global__ __launch_bounds__(256)
void div_fb(const float* __restrict__ sums, const float* __restrict__ counts,
            float* __restrict__ out)
{
    int i = blockIdx.x * 256 + threadIdx.x;
    if (i < BD) out[i] = sums[i] / fmaxf(counts[i >> 7], 1.0f);
}

// ---------------------------------------------------------------------------
extern "C" void kernel_launch(void* const* d_in, const int* in_sizes, int n_in,
                              void* d_out, int out_size, void* d_ws, size_t ws_size,
                              hipStream_t stream)
{
    const float* x     = (const float*)d_in[0];
    const int*   batch = (const int*)d_in[1];
    const int    N     = in_sizes[1];

    // ws layout: [start: 32 ints][sums: BD floats][partial: MB_BLOCKS*BD floats]
    int*   start   = (int*)d_ws;
    float* sums    = (float*)d_ws + 32;
    float* partial = (float*)d_ws + 32 + BD;
    const size_t need = (size_t)(32 + BD + (size_t)MB_BLOCKS * BD) * sizeof(float);

    if (ws_size >= need) {
        boundary_kernel<<<(N / 4 + 255) / 256, 256, 0, stream>>>(batch, N, start, sums);
        pool_main<<<MB_BLOCKS, MB_THREADS, 0, stream>>>(x, start, partial);
        stage2_kernel<<<128, 256, 0, stream>>>(partial, sums);
        div_kernel<<<8, 256, 0, stream>>>(sums, start, (float*)d_out);
    } else {
        float* fsums   = (float*)d_ws;
        float* fcounts = fsums + BD;
        hipMemsetAsync(d_ws, 0, (BD + BSEG) * sizeof(float), stream);
        pool_sum_fb<<<2048, 256, 0, stream>>>(x, batch, fsums, fcounts, N, 2048);
        div_fb<<<8, 256, 0, stream>>>(fsums, fcounts, (float*)d_out);
    }
}

// Round 9
// 167.690 us; speedup vs baseline: 1.2642x; 1.0197x over previous
//
#include <hip/hip_runtime.h>

// Segment-mean pool: x [N][128] f32, batch [N] int32 (sorted, 0..15),
// out [16][128] f32 = segment_sum(x)/max(count,1).
//
// 3-dispatch pipeline:
//   k1 boundary_kernel: int4 scan of sorted batch -> 17 boundary offsets;
//      block 0 also zeroes the sums accumulator.
//   k2 pool_main: per segment, all 524288 threads (full occupancy) grid-stride
//      linearly over its contiguous float4 range with NON-TEMPORAL loads
//      (read-once stream, ~6.5 TB/s) -> block LDS partials, flushed straight
//      to global sums via atomicAdd (no intermediate partial buffer).
//   k3 div: divide by counts (boundary diffs), write out.

#define D       128
#define D4      32
#define BSEG    16
#define BD      (BSEG * D)          // 2048

#define MB_BLOCKS   512
#define MB_THREADS  1024
#define GSTRIDE     (MB_BLOCKS * MB_THREADS)   // 524288 float4s, ≡0 mod 32

typedef float v4f __attribute__((ext_vector_type(4)));

// ---- k1: boundaries + sums zero-init.
__global__ __launch_bounds__(256)
void boundary_kernel(const int* __restrict__ batch, int N,
                     int* __restrict__ start, float* __restrict__ sums)
{
    if (blockIdx.x == 0) {
        for (int i = threadIdx.x; i < BD; i += 256) sums[i] = 0.0f;
    }

    int t  = blockIdx.x * 256 + threadIdx.x;
    int i0 = t * 4;
    if (i0 >= N) return;

    int e[5];
    if (i0 + 4 <= N) {
        int4 b = *(const int4*)(batch + i0);
        e[0] = b.x; e[1] = b.y; e[2] = b.z; e[3] = b.w;
    } else {
        for (int k = 0; k < 4; ++k) e[k] = (i0 + k < N) ? batch[i0 + k] : batch[N - 1];
    }
    bool last = (i0 + 4 >= N);
    e[4] = last ? BSEG : batch[i0 + 4];

    if (i0 == 0) {
        int b0 = min(max(e[0], 0), BSEG - 1);
        for (int s = 0; s <= b0; ++s) start[s] = 0;
    }
    for (int k = 0; k < 4; ++k) {
        int a = min(max(e[k], 0), BSEG - 1);
        int b = (k == 3) ? (last ? BSEG : min(max(e[4], 0), BSEG - 1))
                         : min(max(e[k + 1], 0), BSEG - 1);
        int pos = i0 + k + 1; if (pos > N) pos = N;
        for (int s = a + 1; s <= b; ++s) start[s] = pos;
    }
}

// ---- k2: main streaming sum (full occupancy, nontemporal read-once stream,
//          direct atomic flush).
__global__ __launch_bounds__(MB_THREADS, 8)
void pool_main(const float* __restrict__ x, const int* __restrict__ start,
               float* __restrict__ sums)
{
    __shared__ float lds_sum[BSEG][D];
    __shared__ int   lds_st[BSEG + 1];

    const int tid = threadIdx.x;
    for (int i = tid; i < BD; i += MB_THREADS) ((float*)lds_sum)[i] = 0.0f;
    if (tid <= BSEG) lds_st[tid] = start[tid];
    __syncthreads();

    const int gtid = blockIdx.x * MB_THREADS + tid;
    const int col4 = tid & (D4 - 1);      // constant column (GSTRIDE ≡ 0 mod 32)
    const int lane = tid & 63;

    const v4f* __restrict__ x4 = (const v4f*)x;

    #pragma unroll 1
    for (int s = 0; s < BSEG; ++s) {
        const int i0 = lds_st[s] * D4 + gtid;
        const int e1 = lds_st[s + 1] * D4;          // max 64M, fits int
        v4f a = (v4f)0.0f;
        for (int i = i0; i < e1; i += GSTRIDE) {
            v4f v = __builtin_nontemporal_load(x4 + i);
            a += v;
        }
        // lanes l and l+32 hold the same column: fold within wave
        a.x += __shfl_down(a.x, 32);
        a.y += __shfl_down(a.y, 32);
        a.z += __shfl_down(a.z, 32);
        a.w += __shfl_down(a.w, 32);
        if (lane < 32) {
            atomicAdd(&lds_sum[s][col4 * 4 + 0], a.x);
            atomicAdd(&lds_sum[s][col4 * 4 + 1], a.y);
            atomicAdd(&lds_sum[s][col4 * 4 + 2], a.z);
            atomicAdd(&lds_sum[s][col4 * 4 + 3], a.w);
        }
    }
    __syncthreads();

    // direct flush: 2 atomics per thread, fire-and-forget
    for (int i = tid; i < BD; i += MB_THREADS)
        atomicAdd(&sums[i], ((const float*)lds_sum)[i]);
}

// ---- k3: divide by counts derived from boundaries.
__global__ __launch_bounds__(256)
void div_kernel(const float* __restrict__ sums, const int* __restrict__ start,
                float* __restrict__ out)
{
    int i = blockIdx.x * 256 + threadIdx.x;
    if (i < BD) {
        int s = i >> 7;
        float c = (float)(start[s + 1] - start[s]);
        out[i] = sums[i] / fmaxf(c, 1.0f);
    }
}

// ---------------- fallback (round-1 kernel) if ws is too small --------------
__global__ __launch_bounds__(256)
void pool_sum_fb(const float* __restrict__ x, const int* __restrict__ batch,
                 float* __restrict__ sums, float* __restrict__ counts,
                 int N, int nblocks)
{
    __shared__ float lds_sum[BSEG][D];
    __shared__ float lds_cnt[BSEG];
    const int tid = threadIdx.x;
    for (int i = tid; i < BD; i += 256) ((float*)lds_sum)[i] = 0.0f;
    if (tid < BSEG) lds_cnt[tid] = 0.0f;
    __syncthreads();

    const int chunk = (N + nblocks - 1) / nblocks;
    const int r0 = blockIdx.x * chunk;
    int r1 = r0 + chunk; if (r1 > N) r1 = N;
    const int col4 = tid & (D4 - 1);
    const int rlane = tid >> 5;
    const float4* x4 = (const float4*)x;

    float4 acc = make_float4(0.f, 0.f, 0.f, 0.f);
    int cnt = 0, cur = -1;
    for (int r = r0 + rlane; r < r1; r += 8) {
        int seg = batch[r];
        if (seg != cur) {
            if (cur >= 0) {
                atomicAdd(&lds_sum[cur][col4 * 4 + 0], acc.x);
                atomicAdd(&lds_sum[cur][col4 * 4 + 1], acc.y);
                atomicAdd(&lds_sum[cur][col4 * 4 + 2], acc.z);
                atomicAdd(&lds_sum[cur][col4 * 4 + 3], acc.w);
                if (col4 == 0) atomicAdd(&lds_cnt[cur], (float)cnt);
            }
            acc = make_float4(0.f, 0.f, 0.f, 0.f); cnt = 0;
            cur = (seg >= 0 && seg < BSEG) ? seg : -1;
        }
        if (cur >= 0) {
            float4 v = x4[(long)r * D4 + col4];
            acc.x += v.x; acc.y += v.y; acc.z += v.z; acc.w += v.w; cnt++;
        }
    }
    if (cur >= 0) {
        atomicAdd(&lds_sum[cur][col4 * 4 + 0], acc.x);
        atomicAdd(&lds_sum[cur][col4 * 4 + 1], acc.y);
        atomicAdd(&lds_sum[cur][col4 * 4 + 2], acc.z);
        atomicAdd(&lds_sum[cur][col4 * 4 + 3], acc.w);
        if (col4 == 0) atomicAdd(&lds_cnt[cur], (float)cnt);
    }
    __syncthreads();
    for (int i = tid; i < BD; i += 256) {
        float v = ((float*)lds_sum)[i];
        if (v != 0.0f) atomicAdd(&sums[i], v);
    }
    if (tid < BSEG) {
        float c = lds_cnt[tid];
        if (c != 0.0f) atomicAdd(&counts[tid], c);
    }
}

__global__ __launch_bounds__(256)
void div_fb(const float* __restrict__ sums, const float* __restrict__ counts,
            float* __restrict__ out)
{
    int i = blockIdx.x * 256 + threadIdx.x;
    if (i < BD) out[i] = sums[i] / fmaxf(counts[i >> 7], 1.0f);
}

// ---------------------------------------------------------------------------
extern "C" void kernel_launch(void* const* d_in, const int* in_sizes, int n_in,
                              void* d_out, int out_size, void* d_ws, size_t ws_size,
                              hipStream_t stream)
{
    const float* x     = (const float*)d_in[0];
    const int*   batch = (const int*)d_in[1];
    const int    N     = in_sizes[1];

    // ws layout: [start: 32 ints][sums: BD floats]
    int*   start = (int*)d_ws;
    float* sums  = (float*)d_ws + 32;
    const size_t need = (size_t)(32 + BD) * sizeof(float);

    if (ws_size >= need) {
        boundary_kernel<<<(N / 4 + 255) / 256, 256, 0, stream>>>(batch, N, start, sums);
        pool_main<<<MB_BLOCKS, MB_THREADS, 0, stream>>>(x, start, sums);
        div_kernel<<<8, 256, 0, stream>>>(sums, start, (float*)d_out);
    } else {
        float* fsums   = (float*)d_ws;
        float* fcounts = fsums + BD;
        hipMemsetAsync(d_ws, 0, (BD + BSEG) * sizeof(float), stream);
        pool_sum_fb<<<2048, 256, 0, stream>>>(x, batch, fsums, fcounts, N, 2048);
        div_fb<<<8, 256, 0, stream>>>(fsums, fcounts, (float*)d_out);
    }
}